// Round 13
// baseline (296.397 us; speedup 1.0000x reference)
//
#include <hip/hip_runtime.h>
#include <hip/hip_bf16.h>
#include <math.h>

#define DIM 128
#define BB 8
#define NN 2048
#define LL 4096
#define KK 8

typedef __hip_bfloat16 bf16;
typedef unsigned long long ull;
typedef __attribute__((ext_vector_type(8))) short short8;
typedef __attribute__((ext_vector_type(4))) float float4v;

__device__ __forceinline__ float toF(float x){ return x; }
__device__ __forceinline__ float toF(bf16 x){ return __bfloat162float(x); }
__device__ __forceinline__ void st(float* p, float v){ *p = v; }
__device__ __forceinline__ void st(bf16*  p, float v){ *p = __float2bfloat16(v); }
__device__ __forceinline__ unsigned short f2bf(float f){
  union { bf16 b; unsigned short u; } cv; cv.b = __float2bfloat16(f); return cv.u;
}
__device__ __forceinline__ float2 ld2bf(const bf16* p){
  const unsigned u = *(const unsigned*)p;
  return make_float2(__uint_as_float(u << 16), __uint_as_float(u & 0xFFFF0000u));
}
__device__ __forceinline__ void st2bf(bf16* p, float a, float b){
  *(unsigned*)p = (unsigned)f2bf(a) | ((unsigned)f2bf(b) << 16);
}

__device__ __forceinline__ float gelu_exact(float x){
  return 0.5f * x * (1.0f + erff(x * 0.70710678118654752f));
}

__device__ __forceinline__ float waveSum64(float v){
  #pragma unroll
  for (int o = 32; o > 0; o >>= 1) v += __shfl_xor(v, o, 64);
  return v;
}
__device__ __forceinline__ float quadSum16(float v){
  #pragma unroll
  for (int o = 8; o > 0; o >>= 1) v += __shfl_xor(v, o, 64);
  return v;
}

__device__ __forceinline__ void topk_insert_u(ull (&m)[KK], ull key){
  m[KK-1] = key;
  #pragma unroll
  for (int t = KK-1; t > 0; --t){
    if (m[t] < m[t-1]){ ull tmp = m[t]; m[t] = m[t-1]; m[t-1] = tmp; }
  }
}

// ---------------- fused setup: binning + weight prep ----------------
#define NC3 125
__device__ __forceinline__ void packOne(const float* __restrict__ src,
                                        bf16* __restrict__ dst, int idx, int nshift){
  const int k = idx >> nshift;
  const int n = idx & ((1 << nshift) - 1);
  const int N = 1 << nshift;
  st(&dst[((size_t)(k>>3)*N + n)*8 + (k&7)], src[idx]);
}

__global__ __launch_bounds__(1024) void setup_all(const float* __restrict__ kv_xyz,
                                                  const float* __restrict__ q_xyz,
                                                  float4* __restrict__ bpts,
                                                  int* __restrict__ offs,
                                                  int* __restrict__ qsrt,
                                                  const float* __restrict__ Wlin,
                                                  const float* __restrict__ Wff1,
                                                  const float* __restrict__ Wff2,
                                                  const float* __restrict__ Wsrc,
                                                  const float* __restrict__ Wdst,
                                                  const float* __restrict__ Wattn,
                                                  bf16* __restrict__ WlinP,
                                                  bf16* __restrict__ Wff1P,
                                                  bf16* __restrict__ Wff2P,
                                                  bf16* __restrict__ WsaP,
                                                  bf16* __restrict__ WdaP)
{
  __shared__ int cnt[NC3];
  __shared__ int off[NC3+1];
  __shared__ float row[8][DIM];
  const int bid = blockIdx.x;
  const int tid = threadIdx.x;
  if (bid < 16){
    const int b   = bid & 7;
    const int role= bid >> 3;
    if (tid < NC3) cnt[tid] = 0;
    __syncthreads();
    if (role == 0){
      const float* kvp = kv_xyz + (size_t)b * LL * 3;
      float px[4], py[4], pz[4]; int pc[4];
      #pragma unroll
      for (int i = 0; i < 4; i++){
        const int e = tid + i*1024;
        px[i] = kvp[3*e]; py[i] = kvp[3*e+1]; pz[i] = kvp[3*e+2];
        const int cx = min((int)(px[i]*5.f), 4);
        const int cy = min((int)(py[i]*5.f), 4);
        const int cz = min((int)(pz[i]*5.f), 4);
        pc[i] = (cz*5 + cy)*5 + cx;
        atomicAdd(&cnt[pc[i]], 1);
      }
      __syncthreads();
      if (tid == 0){
        int acc = 0;
        for (int c = 0; c < NC3; c++){ off[c] = acc; acc += cnt[c]; }
        off[NC3] = acc;
      }
      __syncthreads();
      if (tid < NC3) cnt[tid] = 0;
      __syncthreads();
      float4* dst = bpts + (size_t)b * LL;
      #pragma unroll
      for (int i = 0; i < 4; i++){
        const int e = tid + i*1024;
        const int pos = off[pc[i]] + atomicAdd(&cnt[pc[i]], 1);
        dst[pos] = make_float4(px[i], py[i], pz[i], __int_as_float(e));
      }
      if (tid < NC3 + 1) offs[b*126 + tid] = off[tid];
    } else {
      const float* qp = q_xyz + (size_t)b * NN * 3;
      int pc[2];
      #pragma unroll
      for (int i = 0; i < 2; i++){
        const int e = tid + i*1024;
        const float x = qp[3*e], y = qp[3*e+1], z = qp[3*e+2];
        const int cx = min((int)(x*5.f), 4);
        const int cy = min((int)(y*5.f), 4);
        const int cz = min((int)(z*5.f), 4);
        pc[i] = (cz*5 + cy)*5 + cx;
        atomicAdd(&cnt[pc[i]], 1);
      }
      __syncthreads();
      if (tid == 0){
        int acc = 0;
        for (int c = 0; c < NC3; c++){ off[c] = acc; acc += cnt[c]; }
        off[NC3] = acc;
      }
      __syncthreads();
      if (tid < NC3) cnt[tid] = 0;
      __syncthreads();
      int* dst = qsrt + (size_t)b * NN;
      #pragma unroll
      for (int i = 0; i < 2; i++){
        const int e = tid + i*1024;
        const int pos = off[pc[i]] + atomicAdd(&cnt[pc[i]], 1);
        dst[pos] = e;
      }
    }
  } else if (bid < 304){
    int i = (bid - 16)*1024 + tid;
    if (i < 32768){
      const int l = i >> 14, r = i & 16383;
      packOne(Wlin + (size_t)l*16384, WlinP + (size_t)l*16384, r, 7);
    } else if (i < 163840){
      i -= 32768;
      const int l = i >> 16, r = i & 65535;
      packOne(Wff1 + (size_t)l*65536, Wff1P + (size_t)l*65536, r, 9);
    } else {
      i -= 163840;
      const int l = i >> 16, r = i & 65535;
      packOne(Wff2 + (size_t)l*65536, Wff2P + (size_t)l*65536, r, 7);
    }
  } else {
    const int grp = tid >> 7;
    const int c = tid & 127;
    const int tt = (bid - 304)*8 + grp;
    const int r = tt & 127, which = (tt >> 7) & 1, lay = tt >> 8;
    const float* Wx = (which ? Wdst : Wsrc) + (size_t)lay*DIM*DIM;
    const float* Wa = Wattn + (size_t)lay*DIM*DIM;
    row[grp][c] = Wx[r*DIM + c];
    __syncthreads();
    float acc = 0.f;
    for (int j = 0; j < DIM; j++) acc = fmaf(row[grp][j], Wa[j*DIM + c], acc);
    bf16* dst = (which ? WdaP : WsaP) + (size_t)lay*DIM*DIM;
    st(&dst[((size_t)(r>>3)*DIM + c)*8 + (r&7)], acc);
  }
}

// ---------------- helpers for GEMM roles ----------------
__device__ __forceinline__ void stage_A_f32(const float* __restrict__ A, size_t r0,
                                            int kd, int kc, unsigned short* As, int tid){
  #pragma unroll
  for (int i = 0; i < 8; i++){
    const int f = tid + i*256;
    const int row = f >> 5, c4 = (f & 31) * 4;
    const float4 v = *(const float4*)&A[(r0+row)*kd + kc + c4];
    uint2 u;
    u.x = (unsigned)f2bf(v.x) | ((unsigned)f2bf(v.y) << 16);
    u.y = (unsigned)f2bf(v.z) | ((unsigned)f2bf(v.w) << 16);
    *(uint2*)&As[row*136 + c4] = u;
  }
}
__device__ __forceinline__ void stage_A_bf16(const bf16* __restrict__ A, size_t r0,
                                             int kd, int kc, unsigned short* As, int tid){
  #pragma unroll
  for (int i = 0; i < 8; i++){
    const int f = tid + i*256;
    const int row = f >> 5, c4 = (f & 31) * 4;
    *(uint2*)&As[row*136 + c4] = *(const uint2*)&A[(r0+row)*kd + kc + c4];
  }
}

// ---------------- MERGED: knn scan (2048 blks) + kv/qA GEMMs (1280 blks) ----------------
// Interleaved block roles so VALU-bound knn co-schedules with MFMA-bound GEMM.
#define QBLK 8
#define SPL 32
__global__ __launch_bounds__(256) void knn_gemm(const float* __restrict__ q_xyz,
                                                const float4* __restrict__ bpts,
                                                const int* __restrict__ offs,
                                                const int* __restrict__ qsrt,
                                                int* __restrict__ idx,
                                                const float* __restrict__ kvf,
                                                const float* __restrict__ q_feat,
                                                const bf16* __restrict__ WsaP,
                                                const bf16* __restrict__ WlinP,
                                                const bf16* __restrict__ WdaP0,
                                                const float* __restrict__ b_lin,
                                                bf16* __restrict__ srcA0,
                                                bf16* __restrict__ linp0,
                                                bf16* __restrict__ srcA1,
                                                bf16* __restrict__ linp1,
                                                bf16* __restrict__ qA)
{
  __shared__ __align__(16) unsigned char smem[17408];
  const int bid = blockIdx.x;
  const int tid = threadIdx.x;
  bool isGemm; int rid;
  if (bid < 2560){ isGemm = !(bid & 1); rid = bid >> 1; }
  else { isGemm = false; rid = 1280 + (bid - 2560); }

  if (isGemm){
    unsigned short* As = (unsigned short*)smem;
    const int wid = tid >> 6, ln = tid & 63, qd = ln >> 4, cl = ln & 15;
    if (rid < 1024){
      // dual kv GEMM, layer = rid>=512
      const int lay = rid >> 9;
      const size_t r0 = (size_t)(rid & 511) * 64;
      const bf16* Wp0 = WsaP  + (size_t)lay * DIM * DIM;
      const bf16* Wp1 = WlinP + (size_t)lay * DIM * DIM;
      const float* bias1 = b_lin + lay * DIM;
      bf16* Y0 = lay ? srcA1 : srcA0;
      bf16* Y1 = lay ? linp1 : linp0;
      stage_A_f32(kvf, r0, 128, 0, As, tid);
      __syncthreads();
      float4v ac0[8], ac1[8];
      #pragma unroll
      for (int t = 0; t < 8; t++){ ac0[t] = (float4v){0.f,0.f,0.f,0.f}; ac1[t] = (float4v){0.f,0.f,0.f,0.f}; }
      #pragma unroll
      for (int ks = 0; ks < 4; ks++){
        const short8 a = *(const short8*)&As[(wid*16 + cl)*136 + (ks*4 + qd)*8];
        const size_t wo = (size_t)(ks*4 + qd)*DIM + cl;
        const short8* wb0 = (const short8*)Wp0 + wo;
        const short8* wb1 = (const short8*)Wp1 + wo;
        #pragma unroll
        for (int t = 0; t < 8; t++){
          const short8 b0 = wb0[t*16];
          ac0[t] = __builtin_amdgcn_mfma_f32_16x16x32_bf16(a, b0, ac0[t], 0, 0, 0);
          const short8 b1 = wb1[t*16];
          ac1[t] = __builtin_amdgcn_mfma_f32_16x16x32_bf16(a, b1, ac1[t], 0, 0, 0);
        }
      }
      #pragma unroll
      for (int t = 0; t < 8; t++){
        const int col = t*16 + cl;
        const float bv = bias1[col];
        #pragma unroll
        for (int r = 0; r < 4; r++){
          const size_t row = r0 + wid*16 + qd*4 + r;
          st(&Y0[row*DIM + col], ac0[t][r]);
          st(&Y1[row*DIM + col], ac1[t][r] + bv);
        }
      }
    } else {
      // qA0 = q_feat @ WdaP0
      const size_t r0 = (size_t)(rid - 1024) * 64;
      stage_A_f32(q_feat, r0, 128, 0, As, tid);
      __syncthreads();
      float4v acc[8];
      #pragma unroll
      for (int t = 0; t < 8; t++) acc[t] = (float4v){0.f,0.f,0.f,0.f};
      #pragma unroll
      for (int ks = 0; ks < 4; ks++){
        const short8 a = *(const short8*)&As[(wid*16 + cl)*136 + (ks*4 + qd)*8];
        const short8* wb = (const short8*)WdaP0 + (size_t)(ks*4 + qd)*DIM + cl;
        #pragma unroll
        for (int t = 0; t < 8; t++){
          const short8 b = wb[t*16];
          acc[t] = __builtin_amdgcn_mfma_f32_16x16x32_bf16(a, b, acc[t], 0, 0, 0);
        }
      }
      #pragma unroll
      for (int t = 0; t < 8; t++){
        const int col = t*16 + cl;
        #pragma unroll
        for (int r = 0; r < 4; r++){
          const size_t row = r0 + wid*16 + qd*4 + r;
          st(&qA[row*DIM + col], acc[t][r]);
        }
      }
    }
  } else {
    // knn role: rid in [0,2048)
    ull* cd = (ull*)smem;   // QBLK*257 ull = 16448 B
    const int s    = tid & 31;
    const int qloc = tid >> 5;
    const int b    = rid >> 8;
    const int qbase = (rid & 255) * QBLK;
    const int qid = qsrt[b*NN + qbase + qloc];
    const size_t qo = ((size_t)b * NN + qid) * 3;
    const float qx = q_xyz[qo], qy = q_xyz[qo+1], qz = q_xyz[qo+2];
    const ull THRKEY = ((ull)0x3D23D70Bu << 32);
    ull kthr = THRKEY;
    ull m[KK];
    #pragma unroll
    for (int k = 0; k < KK; k++) m[k] = ~0ULL;
    const int qcx = min((int)(qx*5.f), 4);
    const int qcy = min((int)(qy*5.f), 4);
    const int qcz = min((int)(qz*5.f), 4);
    const int* ofb = offs + b*126;
    const float4* bp = bpts + (size_t)b * LL;
    const int cx0 = max(qcx-1, 0), cx1 = min(qcx+1, 4);
    for (int cz = max(qcz-1,0); cz <= min(qcz+1,4); cz++){
      for (int cy = max(qcy-1,0); cy <= min(qcy+1,4); cy++){
        const int rowc = (cz*5 + cy)*5;
        const int pend = ofb[rowc + cx1 + 1];
        int p = ofb[rowc + cx0] + s;
        if (p < pend){
          float4 pt = bp[p];
          while (true){
            const int pn = p + SPL;
            const bool hn = pn < pend;
            float4 nx;
            if (hn) nx = bp[pn];
            const float dx = qx - pt.x, dy = qy - pt.y, dz = qz - pt.z;
            const float d2 = dx*dx + dy*dy + dz*dz;
            const ull key = ((ull)__float_as_uint(d2) << 32) | (unsigned)__float_as_int(pt.w);
            if (key < kthr){
              topk_insert_u(m, key);
              kthr = (m[KK-1] < THRKEY) ? m[KK-1] : THRKEY;
            }
            if (!hn) break;
            pt = nx; p = pn;
          }
        }
      }
    }
    #pragma unroll
    for (int k = 0; k < KK; k++) cd[qloc*257 + k*32 + s] = m[k];
    __syncthreads();
    if (tid < 64){
      const int q = tid >> 3, g = tid & 7;
      ull mm[KK];
      #pragma unroll
      for (int k = 0; k < KK; k++) mm[k] = ~0ULL;
      #pragma unroll
      for (int u = 0; u < 4; u++){
        const int sl = g + 8*u;
        #pragma unroll
        for (int k = 0; k < KK; k++){
          const ull key = cd[q*257 + k*32 + sl];
          if (key < mm[KK-1]) topk_insert_u(mm, key);
        }
      }
      #pragma unroll
      for (int k = 0; k < KK; k++) cd[q*257 + k*32 + g] = mm[k];
      if (tid < QBLK){
        ull f[KK];
        #pragma unroll
        for (int k = 0; k < KK; k++) f[k] = ~0ULL;
        #pragma unroll
        for (int k = 0; k < 8; k++)
          for (int g2 = 0; g2 < 8; g2++){
            const ull key = cd[tid*257 + k*32 + g2];
            if (key < f[KK-1]) topk_insert_u(f, key);
          }
        const int oq = b * NN + qsrt[b*NN + qbase + tid];
        #pragma unroll
        for (int k = 0; k < KK; k++) idx[oq*KK + k] = (int)(unsigned)(f[k] & 0xFFFFFFFFu);
      }
    }
  }
}

// ---------------- standalone MFMA GEMMs (FF1, qA1) ----------------
template<typename TA, int NDIM, bool GELU>
__global__ __launch_bounds__(256) void mfma_single(const TA* __restrict__ A,
                                                   const bf16* __restrict__ Wp,
                                                   const float* __restrict__ bias,
                                                   bf16* __restrict__ Y)
{
  __shared__ __align__(16) unsigned short As[64*136];
  const int tid = threadIdx.x;
  const size_t r0 = (size_t)blockIdx.x * 64;
  const int nblk = blockIdx.y * 128;
  if (sizeof(TA) == 4) stage_A_f32((const float*)A, r0, 128, 0, As, tid);
  else                 stage_A_bf16((const bf16*)A, r0, 128, 0, As, tid);
  __syncthreads();
  const int wid = tid >> 6, ln = tid & 63, qd = ln >> 4, cl = ln & 15;
  float4v acc[8];
  #pragma unroll
  for (int t = 0; t < 8; t++) acc[t] = (float4v){0.f,0.f,0.f,0.f};
  #pragma unroll
  for (int ks = 0; ks < 4; ks++){
    const short8 a = *(const short8*)&As[(wid*16 + cl)*136 + (ks*4 + qd)*8];
    const short8* wb = (const short8*)Wp + (size_t)(ks*4 + qd)*NDIM + nblk + cl;
    #pragma unroll
    for (int t = 0; t < 8; t++){
      const short8 b = wb[t*16];
      acc[t] = __builtin_amdgcn_mfma_f32_16x16x32_bf16(a, b, acc[t], 0, 0, 0);
    }
  }
  #pragma unroll
  for (int t = 0; t < 8; t++){
    const int col = nblk + t*16 + cl;
    const float bv = bias ? bias[col] : 0.f;
    #pragma unroll
    for (int r = 0; r < 4; r++){
      const size_t row = r0 + wid*16 + qd*4 + r;
      float v = acc[t][r] + bv;
      if (GELU) v = gelu_exact(v);
      st(&Y[row*NDIM + col], v);
    }
  }
}

__global__ __launch_bounds__(256) void mfma_ff2ln(const bf16* __restrict__ A,
                                                  const bf16* __restrict__ Wp,
                                                  const float* __restrict__ b2,
                                                  const bf16* __restrict__ resid,
                                                  const float* __restrict__ g,
                                                  const float* __restrict__ bb,
                                                  float* __restrict__ Y)
{
  __shared__ __align__(16) unsigned short As[64*136];
  const int tid = threadIdx.x;
  const size_t r0 = (size_t)blockIdx.x * 64;
  const int wid = tid >> 6, ln = tid & 63, qd = ln >> 4, cl = ln & 15;
  float4v acc[8];
  #pragma unroll
  for (int t = 0; t < 8; t++) acc[t] = (float4v){0.f,0.f,0.f,0.f};
  for (int kc = 0; kc < 512; kc += 128){
    __syncthreads();
    stage_A_bf16(A, r0, 512, kc, As, tid);
    __syncthreads();
    const int k8c = kc >> 3;
    #pragma unroll
    for (int ks = 0; ks < 4; ks++){
      const short8 a = *(const short8*)&As[(wid*16 + cl)*136 + (ks*4 + qd)*8];
      const short8* wb = (const short8*)Wp + (size_t)(k8c + ks*4 + qd)*DIM + cl;
      #pragma unroll
      for (int t = 0; t < 8; t++){
        const short8 b = wb[t*16];
        acc[t] = __builtin_amdgcn_mfma_f32_16x16x32_bf16(a, b, acc[t], 0, 0, 0);
      }
    }
  }
  float v[8][4];
  #pragma unroll
  for (int t = 0; t < 8; t++){
    const int col = t*16 + cl;
    const float bv = b2[col];
    #pragma unroll
    for (int r = 0; r < 4; r++){
      const size_t row = r0 + wid*16 + qd*4 + r;
      v[t][r] = acc[t][r] + bv + toF(resid[row*DIM + col]);
    }
  }
  #pragma unroll
  for (int r = 0; r < 4; r++){
    float s = 0.f;
    #pragma unroll
    for (int t = 0; t < 8; t++) s += v[t][r];
    const float mu = quadSum16(s) * (1.f/DIM);
    float q = 0.f;
    #pragma unroll
    for (int t = 0; t < 8; t++){ const float d = v[t][r] - mu; q += d*d; }
    const float inv = rsqrtf(quadSum16(q) * (1.f/DIM) + 1e-5f);
    const size_t row = r0 + wid*16 + qd*4 + r;
    #pragma unroll
    for (int t = 0; t < 8; t++){
      const int col = t*16 + cl;
      Y[row*DIM + col] = (v[t][r] - mu) * inv * g[col] + bb[col];
    }
  }
}

// ---------------- attention gather + LN1 (sorted order, channel-pair loads) ----------------
__global__ __launch_bounds__(256) void attn_ln1(const bf16* __restrict__ qA,
                                                const bf16* __restrict__ srcA,
                                                const bf16* __restrict__ linp,
                                                const int* __restrict__ idx,
                                                const int* __restrict__ qsrt,
                                                const float* __restrict__ b_attn,
                                                const float* __restrict__ feat,
                                                const float* __restrict__ g,
                                                const float* __restrict__ bb,
                                                bf16* __restrict__ out1)
{
  const int tid = threadIdx.x;
  const int wv = tid >> 6, ln = tid & 63;
  const int sp = blockIdx.x * 4 + wv;
  const int b = sp >> 11;
  const int q = b * NN + qsrt[b*NN + (sp & 2047)];
  const bf16* sbase = srcA + (size_t)b * LL * DIM;
  const bf16* vbase = linp + (size_t)b * LL * DIM;
  const int c0 = 2*ln;
  const float2 ba = *(const float2*)&b_attn[c0];
  const float2 qa2 = ld2bf(&qA[(size_t)q*DIM + c0]);
  const float qa0 = qa2.x + ba.x, qa1 = qa2.y + ba.y;
  int ids[KK]; float l0[KK], l1[KK];
  float m0 = -1e30f, m1 = -1e30f;
  #pragma unroll
  for (int k = 0; k < KK; k++){
    const int id = idx[q*KK + k]; ids[k] = id;
    if (id >= 0){
      const float2 s2 = ld2bf(&sbase[(size_t)id*DIM + c0]);
      l0[k] = fmaxf(qa0 - s2.x, 0.f); m0 = fmaxf(m0, l0[k]);
      l1[k] = fmaxf(qa1 - s2.y, 0.f); m1 = fmaxf(m1, l1[k]);
    } else { l0[k] = 0.f; l1[k] = 0.f; }
  }
  float sum0 = 0.f, sum1 = 0.f, upd0 = 0.f, upd1 = 0.f;
  #pragma unroll
  for (int k = 0; k < KK; k++) if (ids[k] >= 0){
    const float e0 = expf(l0[k] - m0); l0[k] = e0; sum0 += e0;
    const float e1 = expf(l1[k] - m1); l1[k] = e1; sum1 += e1;
  }
  if (sum0 > 0.f){
    const float i0 = 1.f / sum0, i1 = 1.f / sum1;
    #pragma unroll
    for (int k = 0; k < KK; k++) if (ids[k] >= 0){
      const float2 v2 = ld2bf(&vbase[(size_t)ids[k]*DIM + c0]);
      upd0 = fmaf(l0[k]*i0, v2.x, upd0);
      upd1 = fmaf(l1[k]*i1, v2.y, upd1);
    }
  }
  const float2 f2 = *(const float2*)&feat[(size_t)q*DIM + c0];
  const float x0 = f2.x + upd0;
  const float x1 = f2.y + upd1;
  const float mu = waveSum64(x0 + x1) * (1.f/DIM);
  const float d0 = x0 - mu, d1 = x1 - mu;
  const float var = waveSum64(d0*d0 + d1*d1) * (1.f/DIM);
  const float inv = rsqrtf(var + 1e-5f);
  const float2 gg = *(const float2*)&g[c0];
  const float2 bbv = *(const float2*)&bb[c0];
  st2bf(&out1[(size_t)q*DIM + c0], d0 * inv * gg.x + bbv.x, d1 * inv * gg.y + bbv.y);
}

extern "C" void kernel_launch(void* const* d_in, const int* in_sizes, int n_in,
                              void* d_out, int out_size, void* d_ws, size_t ws_size,
                              hipStream_t stream)
{
  const float* q_xyz  = (const float*)d_in[0];
  const float* q_feat = (const float*)d_in[1];
  const float* kv_xyz = (const float*)d_in[2];
  const float* kv_feat= (const float*)d_in[3];
  const float* W_lin  = (const float*)d_in[5];
  const float* b_lin  = (const float*)d_in[6];
  const float* W_src  = (const float*)d_in[7];
  const float* W_dst  = (const float*)d_in[8];
  const float* W_attn = (const float*)d_in[9];
  const float* b_attn = (const float*)d_in[10];
  const float* ln1_g  = (const float*)d_in[11];
  const float* ln1_b  = (const float*)d_in[12];
  const float* W_ff1  = (const float*)d_in[13];
  const float* b_ff1  = (const float*)d_in[14];
  const float* W_ff2  = (const float*)d_in[15];
  const float* b_ff2  = (const float*)d_in[16];
  const float* ln2_g  = (const float*)d_in[17];
  const float* ln2_b  = (const float*)d_in[18];
  float* out = (float*)d_out;

  const int MQ  = BB * NN;   // 16384
  const int MKV = BB * LL;   // 32768

  char* p = (char*)d_ws;
  int*    idxb  = (int*)p;    p += (size_t)MQ * KK * 4;
  float4* bpts  = (float4*)p; p += (size_t)BB * LL * 16;
  int*    boffs = (int*)p;    p += (size_t)BB * 126 * 4;
  int*    qsrt  = (int*)p;    p += (size_t)BB * NN * 4;
  bf16*  WsaP  = (bf16*)p;  p += (size_t)2 * DIM * DIM * 2;
  bf16*  WdaP  = (bf16*)p;  p += (size_t)2 * DIM * DIM * 2;
  bf16*  WlinP = (bf16*)p;  p += (size_t)2 * DIM * DIM * 2;
  bf16*  Wff1P = (bf16*)p;  p += (size_t)2 * DIM * 4*DIM * 2;
  bf16*  Wff2P = (bf16*)p;  p += (size_t)2 * 4*DIM * DIM * 2;
  float* feat  = (float*)p; p += (size_t)MQ * DIM * 4;        // 8 MB
  bf16*  out1  = (bf16*)p;  p += (size_t)MQ * DIM * 2;        // 4 MB
  bf16*  srcA0 = (bf16*)p;  p += (size_t)MKV * DIM * 2;       // 8 MB
  bf16*  linp0 = (bf16*)p;  p += (size_t)MKV * DIM * 2;       // 8 MB
  bf16*  srcA1 = (bf16*)p;  p += (size_t)MKV * DIM * 2;       // 8 MB
  bf16*  linp1 = (bf16*)p;  p += (size_t)MKV * DIM * 2;       // 8 MB
  bf16*  qA    = (bf16*)p;  p += (size_t)MQ * DIM * 2;        // 4 MB
  bf16*  hbuf  = (bf16*)p;  p += (size_t)MQ * 4*DIM * 2;      // 16 MB  (~65 MB total)

  setup_all<<<368, 1024, 0, stream>>>(kv_xyz, q_xyz, bpts, boffs, qsrt,
                                      W_lin, W_ff1, W_ff2, W_src, W_dst, W_attn,
                                      WlinP, Wff1P, Wff2P, WsaP, WdaP);
  // knn scan co-scheduled with BOTH layers' kv GEMMs + layer-0 qA GEMM
  knn_gemm<<<3328, 256, 0, stream>>>(q_xyz, bpts, boffs, qsrt, idxb,
                                     kv_feat, q_feat, WsaP, WlinP, WdaP,
                                     b_lin, srcA0, linp0, srcA1, linp1, qA);

  for (int i = 0; i < 2; i++){
    const size_t w512 = (size_t)i * DIM * 4*DIM;
    const float* featIn = (i == 0) ? q_feat : feat;
    const bf16* srcA = i ? srcA1 : srcA0;
    const bf16* linp = i ? linp1 : linp0;

    if (i == 1){
      // qA1 = feat @ WdaP1 (layer-1 attention query projection)
      mfma_single<float, 128, false><<<MQ/64, 256, 0, stream>>>(
          feat, WdaP + DIM*DIM, nullptr, qA);
    }
    attn_ln1<<<MQ/4, 256, 0, stream>>>(qA, srcA, linp, idxb, qsrt, b_attn + i*DIM,
                                       featIn, ln1_g + i*DIM, ln1_b + i*DIM, out1);
    mfma_single<bf16, 512, true><<<dim3(MQ/64, 4), 256, 0, stream>>>(
        out1, Wff1P + w512, b_ff1 + i*4*DIM, hbuf);
    float* ydst = (i == 1) ? out : feat;
    mfma_ff2ln<<<MQ/64, 256, 0, stream>>>(hbuf, Wff2P + w512, b_ff2 + i*DIM, out1,
                                          ln2_g + i*DIM, ln2_b + i*DIM, ydst);
  }
}

// Round 14
// 284.798 us; speedup vs baseline: 1.0407x; 1.0407x over previous
//
#include <hip/hip_runtime.h>
#include <hip/hip_bf16.h>
#include <math.h>

#define DIM 128
#define BB 8
#define NN 2048
#define LL 4096
#define KK 8

typedef __hip_bfloat16 bf16;
typedef unsigned long long ull;
typedef __attribute__((ext_vector_type(8))) short short8;
typedef __attribute__((ext_vector_type(4))) float float4v;

__device__ __forceinline__ float toF(float x){ return x; }
__device__ __forceinline__ float toF(bf16 x){ return __bfloat162float(x); }
__device__ __forceinline__ void st(float* p, float v){ *p = v; }
__device__ __forceinline__ void st(bf16*  p, float v){ *p = __float2bfloat16(v); }
__device__ __forceinline__ unsigned short f2bf(float f){
  union { bf16 b; unsigned short u; } cv; cv.b = __float2bfloat16(f); return cv.u;
}
__device__ __forceinline__ float2 ld2bf(const bf16* p){
  const unsigned u = *(const unsigned*)p;
  return make_float2(__uint_as_float(u << 16), __uint_as_float(u & 0xFFFF0000u));
}
__device__ __forceinline__ void st2bf(bf16* p, float a, float b){
  *(unsigned*)p = (unsigned)f2bf(a) | ((unsigned)f2bf(b) << 16);
}

__device__ __forceinline__ float gelu_exact(float x){
  return 0.5f * x * (1.0f + erff(x * 0.70710678118654752f));
}

__device__ __forceinline__ float waveSum64(float v){
  #pragma unroll
  for (int o = 32; o > 0; o >>= 1) v += __shfl_xor(v, o, 64);
  return v;
}
__device__ __forceinline__ float quadSum16(float v){
  #pragma unroll
  for (int o = 8; o > 0; o >>= 1) v += __shfl_xor(v, o, 64);
  return v;
}

__device__ __forceinline__ void topk_insert_u(ull (&m)[KK], ull key){
  m[KK-1] = key;
  #pragma unroll
  for (int t = KK-1; t > 0; --t){
    if (m[t] < m[t-1]){ ull tmp = m[t]; m[t] = m[t-1]; m[t-1] = tmp; }
  }
}

// ---------------- fused setup: binning + weight prep ----------------
#define NC3 125
__device__ __forceinline__ void packOne(const float* __restrict__ src,
                                        bf16* __restrict__ dst, int idx, int nshift){
  const int k = idx >> nshift;
  const int n = idx & ((1 << nshift) - 1);
  const int N = 1 << nshift;
  st(&dst[((size_t)(k>>3)*N + n)*8 + (k&7)], src[idx]);
}

__global__ __launch_bounds__(1024) void setup_all(const float* __restrict__ kv_xyz,
                                                  const float* __restrict__ q_xyz,
                                                  float4* __restrict__ bpts,
                                                  int* __restrict__ offs,
                                                  int* __restrict__ qsrt,
                                                  const float* __restrict__ Wlin,
                                                  const float* __restrict__ Wff1,
                                                  const float* __restrict__ Wff2,
                                                  const float* __restrict__ Wsrc,
                                                  const float* __restrict__ Wdst,
                                                  const float* __restrict__ Wattn,
                                                  bf16* __restrict__ WlinP,
                                                  bf16* __restrict__ Wff1P,
                                                  bf16* __restrict__ Wff2P,
                                                  bf16* __restrict__ WsaP,
                                                  bf16* __restrict__ WdaP)
{
  __shared__ int cnt[NC3];
  __shared__ int off[NC3+1];
  __shared__ float row[8][DIM];
  const int bid = blockIdx.x;
  const int tid = threadIdx.x;
  if (bid < 16){
    const int b   = bid & 7;
    const int role= bid >> 3;
    if (tid < NC3) cnt[tid] = 0;
    __syncthreads();
    if (role == 0){
      const float* kvp = kv_xyz + (size_t)b * LL * 3;
      float px[4], py[4], pz[4]; int pc[4];
      #pragma unroll
      for (int i = 0; i < 4; i++){
        const int e = tid + i*1024;
        px[i] = kvp[3*e]; py[i] = kvp[3*e+1]; pz[i] = kvp[3*e+2];
        const int cx = min((int)(px[i]*5.f), 4);
        const int cy = min((int)(py[i]*5.f), 4);
        const int cz = min((int)(pz[i]*5.f), 4);
        pc[i] = (cz*5 + cy)*5 + cx;
        atomicAdd(&cnt[pc[i]], 1);
      }
      __syncthreads();
      if (tid == 0){
        int acc = 0;
        for (int c = 0; c < NC3; c++){ off[c] = acc; acc += cnt[c]; }
        off[NC3] = acc;
      }
      __syncthreads();
      if (tid < NC3) cnt[tid] = 0;
      __syncthreads();
      float4* dst = bpts + (size_t)b * LL;
      #pragma unroll
      for (int i = 0; i < 4; i++){
        const int e = tid + i*1024;
        const int pos = off[pc[i]] + atomicAdd(&cnt[pc[i]], 1);
        dst[pos] = make_float4(px[i], py[i], pz[i], __int_as_float(e));
      }
      if (tid < NC3 + 1) offs[b*126 + tid] = off[tid];
    } else {
      const float* qp = q_xyz + (size_t)b * NN * 3;
      int pc[2];
      #pragma unroll
      for (int i = 0; i < 2; i++){
        const int e = tid + i*1024;
        const float x = qp[3*e], y = qp[3*e+1], z = qp[3*e+2];
        const int cx = min((int)(x*5.f), 4);
        const int cy = min((int)(y*5.f), 4);
        const int cz = min((int)(z*5.f), 4);
        pc[i] = (cz*5 + cy)*5 + cx;
        atomicAdd(&cnt[pc[i]], 1);
      }
      __syncthreads();
      if (tid == 0){
        int acc = 0;
        for (int c = 0; c < NC3; c++){ off[c] = acc; acc += cnt[c]; }
        off[NC3] = acc;
      }
      __syncthreads();
      if (tid < NC3) cnt[tid] = 0;
      __syncthreads();
      int* dst = qsrt + (size_t)b * NN;
      #pragma unroll
      for (int i = 0; i < 2; i++){
        const int e = tid + i*1024;
        const int pos = off[pc[i]] + atomicAdd(&cnt[pc[i]], 1);
        dst[pos] = e;
      }
    }
  } else if (bid < 304){
    int i = (bid - 16)*1024 + tid;
    if (i < 32768){
      const int l = i >> 14, r = i & 16383;
      packOne(Wlin + (size_t)l*16384, WlinP + (size_t)l*16384, r, 7);
    } else if (i < 163840){
      i -= 32768;
      const int l = i >> 16, r = i & 65535;
      packOne(Wff1 + (size_t)l*65536, Wff1P + (size_t)l*65536, r, 9);
    } else {
      i -= 163840;
      const int l = i >> 16, r = i & 65535;
      packOne(Wff2 + (size_t)l*65536, Wff2P + (size_t)l*65536, r, 7);
    }
  } else {
    const int grp = tid >> 7;
    const int c = tid & 127;
    const int tt = (bid - 304)*8 + grp;
    const int r = tt & 127, which = (tt >> 7) & 1, lay = tt >> 8;
    const float* Wx = (which ? Wdst : Wsrc) + (size_t)lay*DIM*DIM;
    const float* Wa = Wattn + (size_t)lay*DIM*DIM;
    row[grp][c] = Wx[r*DIM + c];
    __syncthreads();
    float acc = 0.f;
    for (int j = 0; j < DIM; j++) acc = fmaf(row[grp][j], Wa[j*DIM + c], acc);
    bf16* dst = (which ? WdaP : WsaP) + (size_t)lay*DIM*DIM;
    st(&dst[((size_t)(r>>3)*DIM + c)*8 + (r&7)], acc);
  }
}

// ---------------- knn query: 9-span head prefetch ----------------
#define QBLK 8
#define SPL 32
__global__ __launch_bounds__(256) void knn_query(const float* __restrict__ q_xyz,
                                                 const float4* __restrict__ bpts,
                                                 const int* __restrict__ offs,
                                                 const int* __restrict__ qsrt,
                                                 int* __restrict__ idx)
{
  __shared__ ull cd[QBLK*257];   // 16448 B
  const int tid  = threadIdx.x;
  const int s    = tid & 31;     // split (lanes 0..31 -> 512B coalesced)
  const int qloc = tid >> 5;     // 0..7
  const int b    = blockIdx.y;
  const int qbase = blockIdx.x * QBLK;
  const int qid = qsrt[b*NN + qbase + qloc];
  const size_t qo = ((size_t)b * NN + qid) * 3;
  const float qx = q_xyz[qo], qy = q_xyz[qo+1], qz = q_xyz[qo+2];
  const ull THRKEY = ((ull)0x3D23D70Bu << 32);   // nextafter(0.04f)<<32
  ull kthr = THRKEY;
  ull m[KK];
  #pragma unroll
  for (int k = 0; k < KK; k++) m[k] = ~0ULL;
  const int qcx = min((int)(qx*5.f), 4);
  const int qcy = min((int)(qy*5.f), 4);
  const int qcz = min((int)(qz*5.f), 4);
  const int* ofb = offs + b*126;
  const float4* bp = bpts + (size_t)b * LL;
  const int cx0 = max(qcx-1, 0), cx1 = min(qcx+1, 4);
  // enumerate the 9 candidate spans (fixed unroll -> registers), issue ALL head loads
  int st9[9], en9[9];
  float4 hd[9];
  #pragma unroll
  for (int u = 0; u < 9; u++){
    const int dz = u/3 - 1, dy = u%3 - 1;
    const int cz = qcz + dz, cy = qcy + dy;
    const bool ok = (cz >= 0) & (cz <= 4) & (cy >= 0) & (cy <= 4);
    const int rowc = (cz*5 + cy)*5;
    int a0 = 0, e0 = 0;
    if (ok){ a0 = ofb[rowc + cx0] + s; e0 = ofb[rowc + cx1 + 1]; }
    st9[u] = a0; en9[u] = e0;
    const int pa = (a0 < e0) ? a0 : 0;    // branch-free safe address
    hd[u] = bp[pa];                       // 9 outstanding loads up-front
  }
  #pragma unroll
  for (int u = 0; u < 9; u++){
    int p = st9[u];
    const int e = en9[u];
    if (p < e){
      float4 pt = hd[u];
      while (true){
        const int pn = p + SPL;
        const bool hn = pn < e;
        float4 nx;
        if (hn) nx = bp[pn];              // depth-1 prefetch within span
        const float dx = qx - pt.x, dy = qy - pt.y, dz = qz - pt.z;
        const float d2 = dx*dx + dy*dy + dz*dz;
        const ull key = ((ull)__float_as_uint(d2) << 32) | (unsigned)__float_as_int(pt.w);
        if (key < kthr){
          topk_insert_u(m, key);
          kthr = (m[KK-1] < THRKEY) ? m[KK-1] : THRKEY;
        }
        if (!hn) break;
        pt = nx; p = pn;
      }
    }
  }
  #pragma unroll
  for (int k = 0; k < KK; k++) cd[qloc*257 + k*32 + s] = m[k];
  __syncthreads();
  if (tid < 64){
    const int q = tid >> 3, g = tid & 7;
    ull mm[KK];
    #pragma unroll
    for (int k = 0; k < KK; k++) mm[k] = ~0ULL;
    #pragma unroll
    for (int u = 0; u < 4; u++){
      const int sl = g + 8*u;
      #pragma unroll
      for (int k = 0; k < KK; k++){
        const ull key = cd[q*257 + k*32 + sl];
        if (key < mm[KK-1]) topk_insert_u(mm, key);
      }
    }
    #pragma unroll
    for (int k = 0; k < KK; k++) cd[q*257 + k*32 + g] = mm[k];
    if (tid < QBLK){
      ull f[KK];
      #pragma unroll
      for (int k = 0; k < KK; k++) f[k] = ~0ULL;
      #pragma unroll
      for (int k = 0; k < 8; k++)
        for (int g2 = 0; g2 < 8; g2++){
          const ull key = cd[tid*257 + k*32 + g2];
          if (key < f[KK-1]) topk_insert_u(f, key);
        }
      const int oq = b * NN + qsrt[b*NN + qbase + tid];
      #pragma unroll
      for (int k = 0; k < KK; k++) idx[oq*KK + k] = (int)(unsigned)(f[k] & 0xFFFFFFFFu);
    }
  }
}

// ---------------- GEMM helpers ----------------
__device__ __forceinline__ void stage_A_f32(const float* __restrict__ A, size_t r0,
                                            int kd, int kc, unsigned short* As, int tid){
  #pragma unroll
  for (int i = 0; i < 8; i++){
    const int f = tid + i*256;
    const int row = f >> 5, c4 = (f & 31) * 4;
    const float4 v = *(const float4*)&A[(r0+row)*kd + kc + c4];
    uint2 u;
    u.x = (unsigned)f2bf(v.x) | ((unsigned)f2bf(v.y) << 16);
    u.y = (unsigned)f2bf(v.z) | ((unsigned)f2bf(v.w) << 16);
    *(uint2*)&As[row*136 + c4] = u;
  }
}
__device__ __forceinline__ void stage_A_bf16(const bf16* __restrict__ A, size_t r0,
                                             int kd, int kc, unsigned short* As, int tid){
  #pragma unroll
  for (int i = 0; i < 8; i++){
    const int f = tid + i*256;
    const int row = f >> 5, c4 = (f & 31) * 4;
    *(uint2*)&As[row*136 + c4] = *(const uint2*)&A[(r0+row)*kd + kc + c4];
  }
}

// ---------------- all independent 128-N GEMMs, one launch (1280 blocks) ----------------
// [0,512): dual kv GEMM layer 0; [512,1024): dual kv GEMM layer 1; [1024,1280): qA0.
__global__ __launch_bounds__(256) void gemm_all(const float* __restrict__ kvf,
                                                const float* __restrict__ q_feat,
                                                const bf16* __restrict__ WsaP,
                                                const bf16* __restrict__ WlinP,
                                                const bf16* __restrict__ WdaP0,
                                                const float* __restrict__ b_lin,
                                                bf16* __restrict__ srcA0,
                                                bf16* __restrict__ linp0,
                                                bf16* __restrict__ srcA1,
                                                bf16* __restrict__ linp1,
                                                bf16* __restrict__ qA)
{
  __shared__ __align__(16) unsigned short As[64*136];
  const int bid = blockIdx.x;
  const int tid = threadIdx.x;
  const int wid = tid >> 6, ln = tid & 63, qd = ln >> 4, cl = ln & 15;
  if (bid < 1024){
    const int lay = bid >> 9;
    const size_t r0 = (size_t)(bid & 511) * 64;
    const bf16* Wp0 = WsaP  + (size_t)lay * DIM * DIM;
    const bf16* Wp1 = WlinP + (size_t)lay * DIM * DIM;
    const float* bias1 = b_lin + lay * DIM;
    bf16* Y0 = lay ? srcA1 : srcA0;
    bf16* Y1 = lay ? linp1 : linp0;
    stage_A_f32(kvf, r0, 128, 0, As, tid);
    __syncthreads();
    float4v ac0[8], ac1[8];
    #pragma unroll
    for (int t = 0; t < 8; t++){ ac0[t] = (float4v){0.f,0.f,0.f,0.f}; ac1[t] = (float4v){0.f,0.f,0.f,0.f}; }
    #pragma unroll
    for (int ks = 0; ks < 4; ks++){
      const short8 a = *(const short8*)&As[(wid*16 + cl)*136 + (ks*4 + qd)*8];
      const size_t wo = (size_t)(ks*4 + qd)*DIM + cl;
      const short8* wb0 = (const short8*)Wp0 + wo;
      const short8* wb1 = (const short8*)Wp1 + wo;
      #pragma unroll
      for (int t = 0; t < 8; t++){
        const short8 b0 = wb0[t*16];
        ac0[t] = __builtin_amdgcn_mfma_f32_16x16x32_bf16(a, b0, ac0[t], 0, 0, 0);
        const short8 b1 = wb1[t*16];
        ac1[t] = __builtin_amdgcn_mfma_f32_16x16x32_bf16(a, b1, ac1[t], 0, 0, 0);
      }
    }
    #pragma unroll
    for (int t = 0; t < 8; t++){
      const int col = t*16 + cl;
      const float bv = bias1[col];
      #pragma unroll
      for (int r = 0; r < 4; r++){
        const size_t row = r0 + wid*16 + qd*4 + r;
        st(&Y0[row*DIM + col], ac0[t][r]);
        st(&Y1[row*DIM + col], ac1[t][r] + bv);
      }
    }
  } else {
    const size_t r0 = (size_t)(bid - 1024) * 64;
    stage_A_f32(q_feat, r0, 128, 0, As, tid);
    __syncthreads();
    float4v acc[8];
    #pragma unroll
    for (int t = 0; t < 8; t++) acc[t] = (float4v){0.f,0.f,0.f,0.f};
    #pragma unroll
    for (int ks = 0; ks < 4; ks++){
      const short8 a = *(const short8*)&As[(wid*16 + cl)*136 + (ks*4 + qd)*8];
      const short8* wb = (const short8*)WdaP0 + (size_t)(ks*4 + qd)*DIM + cl;
      #pragma unroll
      for (int t = 0; t < 8; t++){
        const short8 b = wb[t*16];
        acc[t] = __builtin_amdgcn_mfma_f32_16x16x32_bf16(a, b, acc[t], 0, 0, 0);
      }
    }
    #pragma unroll
    for (int t = 0; t < 8; t++){
      const int col = t*16 + cl;
      #pragma unroll
      for (int r = 0; r < 4; r++){
        const size_t row = r0 + wid*16 + qd*4 + r;
        st(&qA[row*DIM + col], acc[t][r]);
      }
    }
  }
}

// ---------------- FF1 (bf16 in, gelu out) ----------------
__global__ __launch_bounds__(256) void mfma_ff1(const bf16* __restrict__ A,
                                                const bf16* __restrict__ Wp,
                                                const float* __restrict__ bias,
                                                bf16* __restrict__ Y)
{
  __shared__ __align__(16) unsigned short As[64*136];
  const int tid = threadIdx.x;
  const size_t r0 = (size_t)blockIdx.x * 64;
  const int nblk = blockIdx.y * 128;
  stage_A_bf16(A, r0, 128, 0, As, tid);
  __syncthreads();
  const int wid = tid >> 6, ln = tid & 63, qd = ln >> 4, cl = ln & 15;
  float4v acc[8];
  #pragma unroll
  for (int t = 0; t < 8; t++) acc[t] = (float4v){0.f,0.f,0.f,0.f};
  #pragma unroll
  for (int ks = 0; ks < 4; ks++){
    const short8 a = *(const short8*)&As[(wid*16 + cl)*136 + (ks*4 + qd)*8];
    const short8* wb = (const short8*)Wp + (size_t)(ks*4 + qd)*512 + nblk + cl;
    #pragma unroll
    for (int t = 0; t < 8; t++){
      const short8 b = wb[t*16];
      acc[t] = __builtin_amdgcn_mfma_f32_16x16x32_bf16(a, b, acc[t], 0, 0, 0);
    }
  }
  #pragma unroll
  for (int t = 0; t < 8; t++){
    const int col = nblk + t*16 + cl;
    const float bv = bias[col];
    #pragma unroll
    for (int r = 0; r < 4; r++){
      const size_t row = r0 + wid*16 + qd*4 + r;
      st(&Y[row*512 + col], gelu_exact(acc[t][r] + bv));
    }
  }
}

// ---------------- FF2 + residual + LN2 (+ optional fused qA_next GEMM) ----------------
template<bool EMITQA>
__global__ __launch_bounds__(256) void mfma_ff2ln(const bf16* __restrict__ A,
                                                  const bf16* __restrict__ Wp,
                                                  const float* __restrict__ b2,
                                                  const bf16* __restrict__ resid,
                                                  const float* __restrict__ g,
                                                  const float* __restrict__ bb,
                                                  float* __restrict__ Y,
                                                  const bf16* __restrict__ WqP,
                                                  bf16* __restrict__ qA)
{
  __shared__ __align__(16) unsigned short As[64*136];
  const int tid = threadIdx.x;
  const size_t r0 = (size_t)blockIdx.x * 64;
  const int wid = tid >> 6, ln = tid & 63, qd = ln >> 4, cl = ln & 15;
  float4v acc[8];
  #pragma unroll
  for (int t = 0; t < 8; t++) acc[t] = (float4v){0.f,0.f,0.f,0.f};
  for (int kc = 0; kc < 512; kc += 128){
    __syncthreads();
    stage_A_bf16(A, r0, 512, kc, As, tid);
    __syncthreads();
    const int k8c = kc >> 3;
    #pragma unroll
    for (int ks = 0; ks < 4; ks++){
      const short8 a = *(const short8*)&As[(wid*16 + cl)*136 + (ks*4 + qd)*8];
      const short8* wb = (const short8*)Wp + (size_t)(k8c + ks*4 + qd)*DIM + cl;
      #pragma unroll
      for (int t = 0; t < 8; t++){
        const short8 b = wb[t*16];
        acc[t] = __builtin_amdgcn_mfma_f32_16x16x32_bf16(a, b, acc[t], 0, 0, 0);
      }
    }
  }
  float v[8][4];
  #pragma unroll
  for (int t = 0; t < 8; t++){
    const int col = t*16 + cl;
    const float bv = b2[col];
    #pragma unroll
    for (int r = 0; r < 4; r++){
      const size_t row = r0 + wid*16 + qd*4 + r;
      v[t][r] = acc[t][r] + bv + toF(resid[row*DIM + col]);
    }
  }
  // LN2 -> overwrite v with normalized output, write f32 Y
  #pragma unroll
  for (int r = 0; r < 4; r++){
    float s = 0.f;
    #pragma unroll
    for (int t = 0; t < 8; t++) s += v[t][r];
    const float mu = quadSum16(s) * (1.f/DIM);
    float q = 0.f;
    #pragma unroll
    for (int t = 0; t < 8; t++){ const float d = v[t][r] - mu; q += d*d; }
    const float inv = rsqrtf(quadSum16(q) * (1.f/DIM) + 1e-5f);
    const size_t row = r0 + wid*16 + qd*4 + r;
    #pragma unroll
    for (int t = 0; t < 8; t++){
      const int col = t*16 + cl;
      const float y = (v[t][r] - mu) * inv * g[col] + bb[col];
      v[t][r] = y;
      Y[row*DIM + col] = y;
    }
  }
  if (EMITQA){
    // round-trip Y (bf16) through LDS, then qA = Ybf @ WqP.
    __syncthreads();   // protect As against the kc-loop's cross-wave readers
    #pragma unroll
    for (int t = 0; t < 8; t++){
      #pragma unroll
      for (int r = 0; r < 4; r++)
        As[(wid*16 + qd*4 + r)*136 + t*16 + cl] = f2bf(v[t][r]);
    }
    // rows wid*16..wid*16+15 are wave-private; per-wave LDS is in-order -> no barrier
    float4v qacc[8];
    #pragma unroll
    for (int t = 0; t < 8; t++) qacc[t] = (float4v){0.f,0.f,0.f,0.f};
    #pragma unroll
    for (int ks = 0; ks < 4; ks++){
      const short8 a = *(const short8*)&As[(wid*16 + cl)*136 + (ks*4 + qd)*8];
      const short8* wb = (const short8*)WqP + (size_t)(ks*4 + qd)*DIM + cl;
      #pragma unroll
      for (int t = 0; t < 8; t++){
        const short8 b = wb[t*16];
        qacc[t] = __builtin_amdgcn_mfma_f32_16x16x32_bf16(a, b, qacc[t], 0, 0, 0);
      }
    }
    #pragma unroll
    for (int t = 0; t < 8; t++){
      const int col = t*16 + cl;
      #pragma unroll
      for (int r = 0; r < 4; r++){
        const size_t row = r0 + wid*16 + qd*4 + r;
        st(&qA[row*DIM + col], qacc[t][r]);
      }
    }
  }
}

// ---------------- attention gather + LN1 (sorted order, channel-pair loads) ----------------
__global__ __launch_bounds__(256) void attn_ln1(const bf16* __restrict__ qA,
                                                const bf16* __restrict__ srcA,
                                                const bf16* __restrict__ linp,
                                                const int* __restrict__ idx,
                                                const int* __restrict__ qsrt,
                                                const float* __restrict__ b_attn,
                                                const float* __restrict__ feat,
                                                const float* __restrict__ g,
                                                const float* __restrict__ bb,
                                                bf16* __restrict__ out1)
{
  const int tid = threadIdx.x;
  const int wv = tid >> 6, ln = tid & 63;
  const int sp = blockIdx.x * 4 + wv;
  const int b = sp >> 11;
  const int q = b * NN + qsrt[b*NN + (sp & 2047)];
  const bf16* sbase = srcA + (size_t)b * LL * DIM;
  const bf16* vbase = linp + (size_t)b * LL * DIM;
  const int c0 = 2*ln;
  const float2 ba = *(const float2*)&b_attn[c0];
  const float2 qa2 = ld2bf(&qA[(size_t)q*DIM + c0]);
  const float qa0 = qa2.x + ba.x, qa1 = qa2.y + ba.y;
  int ids[KK]; float l0[KK], l1[KK];
  float m0 = -1e30f, m1 = -1e30f;
  #pragma unroll
  for (int k = 0; k < KK; k++){
    const int id = idx[q*KK + k]; ids[k] = id;
    if (id >= 0){
      const float2 s2 = ld2bf(&sbase[(size_t)id*DIM + c0]);
      l0[k] = fmaxf(qa0 - s2.x, 0.f); m0 = fmaxf(m0, l0[k]);
      l1[k] = fmaxf(qa1 - s2.y, 0.f); m1 = fmaxf(m1, l1[k]);
    } else { l0[k] = 0.f; l1[k] = 0.f; }
  }
  float sum0 = 0.f, sum1 = 0.f, upd0 = 0.f, upd1 = 0.f;
  #pragma unroll
  for (int k = 0; k < KK; k++) if (ids[k] >= 0){
    const float e0 = expf(l0[k] - m0); l0[k] = e0; sum0 += e0;
    const float e1 = expf(l1[k] - m1); l1[k] = e1; sum1 += e1;
  }
  if (sum0 > 0.f){
    const float i0 = 1.f / sum0, i1 = 1.f / sum1;
    #pragma unroll
    for (int k = 0; k < KK; k++) if (ids[k] >= 0){
      const float2 v2 = ld2bf(&vbase[(size_t)ids[k]*DIM + c0]);
      upd0 = fmaf(l0[k]*i0, v2.x, upd0);
      upd1 = fmaf(l1[k]*i1, v2.y, upd1);
    }
  }
  const float2 f2 = *(const float2*)&feat[(size_t)q*DIM + c0];
  const float x0 = f2.x + upd0;
  const float x1 = f2.y + upd1;
  const float mu = waveSum64(x0 + x1) * (1.f/DIM);
  const float d0 = x0 - mu, d1 = x1 - mu;
  const float var = waveSum64(d0*d0 + d1*d1) * (1.f/DIM);
  const float inv = rsqrtf(var + 1e-5f);
  const float2 gg = *(const float2*)&g[c0];
  const float2 bbv = *(const float2*)&bb[c0];
  st2bf(&out1[(size_t)q*DIM + c0], d0 * inv * gg.x + bbv.x, d1 * inv * gg.y + bbv.y);
}

extern "C" void kernel_launch(void* const* d_in, const int* in_sizes, int n_in,
                              void* d_out, int out_size, void* d_ws, size_t ws_size,
                              hipStream_t stream)
{
  const float* q_xyz  = (const float*)d_in[0];
  const float* q_feat = (const float*)d_in[1];
  const float* kv_xyz = (const float*)d_in[2];
  const float* kv_feat= (const float*)d_in[3];
  const float* W_lin  = (const float*)d_in[5];
  const float* b_lin  = (const float*)d_in[6];
  const float* W_src  = (const float*)d_in[7];
  const float* W_dst  = (const float*)d_in[8];
  const float* W_attn = (const float*)d_in[9];
  const float* b_attn = (const float*)d_in[10];
  const float* ln1_g  = (const float*)d_in[11];
  const float* ln1_b  = (const float*)d_in[12];
  const float* W_ff1  = (const float*)d_in[13];
  const float* b_ff1  = (const float*)d_in[14];
  const float* W_ff2  = (const float*)d_in[15];
  const float* b_ff2  = (const float*)d_in[16];
  const float* ln2_g  = (const float*)d_in[17];
  const float* ln2_b  = (const float*)d_in[18];
  float* out = (float*)d_out;

  const int MQ  = BB * NN;   // 16384
  const int MKV = BB * LL;   // 32768

  char* p = (char*)d_ws;
  int*    idxb  = (int*)p;    p += (size_t)MQ * KK * 4;
  float4* bpts  = (float4*)p; p += (size_t)BB * LL * 16;
  int*    boffs = (int*)p;    p += (size_t)BB * 126 * 4;
  int*    qsrt  = (int*)p;    p += (size_t)BB * NN * 4;
  bf16*  WsaP  = (bf16*)p;  p += (size_t)2 * DIM * DIM * 2;
  bf16*  WdaP  = (bf16*)p;  p += (size_t)2 * DIM * DIM * 2;
  bf16*  WlinP = (bf16*)p;  p += (size_t)2 * DIM * DIM * 2;
  bf16*  Wff1P = (bf16*)p;  p += (size_t)2 * DIM * 4*DIM * 2;
  bf16*  Wff2P = (bf16*)p;  p += (size_t)2 * 4*DIM * DIM * 2;
  float* feat  = (float*)p; p += (size_t)MQ * DIM * 4;
  bf16*  out1  = (bf16*)p;  p += (size_t)MQ * DIM * 2;
  bf16*  srcA0 = (bf16*)p;  p += (size_t)MKV * DIM * 2;
  bf16*  linp0 = (bf16*)p;  p += (size_t)MKV * DIM * 2;
  bf16*  srcA1 = (bf16*)p;  p += (size_t)MKV * DIM * 2;
  bf16*  linp1 = (bf16*)p;  p += (size_t)MKV * DIM * 2;
  bf16*  qA    = (bf16*)p;  p += (size_t)MQ * DIM * 2;
  bf16*  hbuf  = (bf16*)p;  p += (size_t)MQ * 4*DIM * 2;

  setup_all<<<368, 1024, 0, stream>>>(kv_xyz, q_xyz, bpts, boffs, qsrt,
                                      W_lin, W_ff1, W_ff2, W_src, W_dst, W_attn,
                                      WlinP, Wff1P, Wff2P, WsaP, WdaP);
  knn_query<<<dim3(NN/QBLK, BB), 256, 0, stream>>>(q_xyz, bpts, boffs, qsrt, idxb);
  gemm_all<<<1280, 256, 0, stream>>>(kv_feat, q_feat, WsaP, WlinP, WdaP,
                                     b_lin, srcA0, linp0, srcA1, linp1, qA);

  // layer 0
  attn_ln1<<<MQ/4, 256, 0, stream>>>(qA, srcA0, linp0, idxb, qsrt, b_attn,
                                     q_feat, ln1_g, ln1_b, out1);
  mfma_ff1<<<dim3(MQ/64, 4), 256, 0, stream>>>(out1, Wff1P, b_ff1, hbuf);
  // feat = LN2(...); fused: qA <- feat_bf16 @ Wda1
  mfma_ff2ln<true><<<MQ/64, 256, 0, stream>>>(hbuf, Wff2P, b_ff2, out1,
                                              ln2_g, ln2_b, feat,
                                              WdaP + DIM*DIM, qA);
  // layer 1
  attn_ln1<<<MQ/4, 256, 0, stream>>>(qA, srcA1, linp1, idxb, qsrt, b_attn + DIM,
                                     feat, ln1_g + DIM, ln1_b + DIM, out1);
  mfma_ff1<<<dim3(MQ/64, 4), 256, 0, stream>>>(out1, Wff1P + DIM*4*DIM,
                                               b_ff1 + 4*DIM, hbuf);
  mfma_ff2ln<false><<<MQ/64, 256, 0, stream>>>(hbuf, Wff2P + 4*DIM*DIM,
                                               b_ff2 + DIM, out1,
                                               ln2_g + DIM, ln2_b + DIM, out,
                                               nullptr, nullptr);
}